// Round 1
// baseline (808.591 us; speedup 1.0000x reference)
//
#include <hip/hip_runtime.h>

// GCN regressor: 2x (mean-aggregate + linear+ReLU) + per-graph mean + MLP head.
// N=50000 nodes, E=800000 edges, D_IN=128, H1=256, H2=128, G=256. All fp32.

#define NUM_GRAPHS 256

// ---------------- CSR build ----------------

__global__ void count_kernel(const int* __restrict__ dst, int* __restrict__ cnt, int E) {
    int e = blockIdx.x * blockDim.x + threadIdx.x;
    if (e < E) atomicAdd(&cnt[dst[e]], 1);
}

// Single-block exclusive scan of cnt[0..N-1] -> offs[0..N]; 1024 threads.
__global__ void scan_kernel(const int* __restrict__ cnt, int* __restrict__ offs, int N) {
    __shared__ int wsum[16];
    int tid = threadIdx.x;
    int lane = tid & 63;
    int wid = tid >> 6;
    int carry = 0;
    for (int base = 0; base < N; base += 1024) {
        int i = base + tid;
        int v = (i < N) ? cnt[i] : 0;
        int x = v;
        #pragma unroll
        for (int d = 1; d < 64; d <<= 1) {
            int y = __shfl_up(x, d, 64);
            if (lane >= d) x += y;
        }
        if (lane == 63) wsum[wid] = x;
        __syncthreads();
        if (wid == 0) {
            int s = (lane < 16) ? wsum[lane] : 0;
            #pragma unroll
            for (int d = 1; d < 16; d <<= 1) {
                int y = __shfl_up(s, d, 64);
                if (lane >= d) s += y;
            }
            if (lane < 16) wsum[lane] = s;
        }
        __syncthreads();
        int wbase = (wid > 0) ? wsum[wid - 1] : 0;
        if (i < N) offs[i] = carry + wbase + (x - v);
        carry += wsum[15];
        __syncthreads();  // protect wsum before next chunk overwrites
    }
    if (tid == 0) offs[N] = carry;
}

__global__ void scatter_kernel(const int* __restrict__ src, const int* __restrict__ dst,
                               const int* __restrict__ offs, int* __restrict__ cur,
                               int* __restrict__ eidx, int E) {
    int e = blockIdx.x * blockDim.x + threadIdx.x;
    if (e < E) {
        int d = dst[e];
        int p = offs[d] + atomicAdd(&cur[d], 1);
        eidx[p] = src[e];
    }
}

// ---------------- mean aggregation: one wave per dst node ----------------

template <int D>
__global__ void agg_mean_kernel(const float* __restrict__ feat, const int* __restrict__ offs,
                                const int* __restrict__ eidx, float* __restrict__ out, int N) {
    constexpr int VPL = D / 64;  // floats per lane (2 or 4)
    int wave = blockIdx.x * (blockDim.x >> 6) + (threadIdx.x >> 6);
    int lane = threadIdx.x & 63;
    if (wave >= N) return;
    int beg = offs[wave], end = offs[wave + 1];
    float acc[VPL];
    #pragma unroll
    for (int i = 0; i < VPL; ++i) acc[i] = 0.0f;
    for (int j = beg; j < end; ++j) {
        int s = eidx[j];
        const float* row = feat + (size_t)s * D + lane * VPL;
        if constexpr (VPL == 2) {
            float2 v = *(const float2*)row;
            acc[0] += v.x; acc[1] += v.y;
        } else {
            float4 v = *(const float4*)row;
            acc[0] += v.x; acc[1] += v.y; acc[2] += v.z; acc[3] += v.w;
        }
    }
    int deg = end - beg;
    float invd = 1.0f / (float)(deg > 0 ? deg : 1);
    float* orow = out + (size_t)wave * D + lane * VPL;
    if constexpr (VPL == 2) {
        float2 o; o.x = acc[0] * invd; o.y = acc[1] * invd;
        *(float2*)orow = o;
    } else {
        float4 o; o.x = acc[0] * invd; o.y = acc[1] * invd; o.z = acc[2] * invd; o.w = acc[3] * invd;
        *(float4*)orow = o;
    }
}

// ---------------- fp32 GEMM + bias + ReLU: C[N,256] = relu(A[N,K] @ W[K,256] + b) ----------------
// 64 rows x 256 cols per block; 256 threads, each 8 rows x 8 cols.
// K staged to LDS transposed in 128-chunks, row stride 68 (16B aligned, banks spread).

template <int K>
__launch_bounds__(256)
__global__ void gemm_relu_kernel(const float* __restrict__ A, const float* __restrict__ W,
                                 const float* __restrict__ bias, float* __restrict__ C, int N) {
    constexpr int LDA = 68;
    __shared__ float AsT[128 * LDA];  // 34816 B

    int tid = threadIdx.x;
    int tc = tid & 31;   // thread-col: 32 * 8 = 256 cols
    int tr = tid >> 5;   // thread-row: 8 * 8 = 64 rows
    int c0 = tc * 8;
    int rowBase = blockIdx.x * 64;

    float acc[8][8];
    #pragma unroll
    for (int i = 0; i < 8; ++i)
        #pragma unroll
        for (int j = 0; j < 8; ++j) acc[i][j] = 0.0f;

    for (int kc = 0; kc < K; kc += 128) {
        // stage A[rowBase..rowBase+63][kc..kc+127] transposed into AsT[k][r]
        for (int t = tid; t < 128 * 16; t += 256) {
            int k = t & 127;
            int rb = (t >> 7) * 4;
            float v[4];
            #pragma unroll
            for (int j = 0; j < 4; ++j) {
                int gr = rowBase + rb + j;
                v[j] = (gr < N) ? A[(size_t)gr * K + kc + k] : 0.0f;
            }
            float4 pv; pv.x = v[0]; pv.y = v[1]; pv.z = v[2]; pv.w = v[3];
            *(float4*)&AsT[k * LDA + rb] = pv;
        }
        __syncthreads();

        for (int k = 0; k < 128; ++k) {
            float4 a0 = *(const float4*)&AsT[k * LDA + tr * 8];
            float4 a1 = *(const float4*)&AsT[k * LDA + tr * 8 + 4];
            const float* wr = W + (size_t)(kc + k) * 256 + c0;
            float4 w0 = *(const float4*)wr;
            float4 w1 = *(const float4*)(wr + 4);
            float a[8] = {a0.x, a0.y, a0.z, a0.w, a1.x, a1.y, a1.z, a1.w};
            float w[8] = {w0.x, w0.y, w0.z, w0.w, w1.x, w1.y, w1.z, w1.w};
            #pragma unroll
            for (int i = 0; i < 8; ++i)
                #pragma unroll
                for (int j = 0; j < 8; ++j)
                    acc[i][j] += a[i] * w[j];
        }
        __syncthreads();
    }

    float4 bv0 = *(const float4*)&bias[c0];
    float4 bv1 = *(const float4*)&bias[c0 + 4];
    float b[8] = {bv0.x, bv0.y, bv0.z, bv0.w, bv1.x, bv1.y, bv1.z, bv1.w};
    #pragma unroll
    for (int i = 0; i < 8; ++i) {
        int gr = rowBase + tr * 8 + i;
        if (gr < N) {
            float o[8];
            #pragma unroll
            for (int j = 0; j < 8; ++j) o[j] = fmaxf(acc[i][j] + b[j], 0.0f);
            float4 o0; o0.x = o[0]; o0.y = o[1]; o0.z = o[2]; o0.w = o[3];
            float4 o1; o1.x = o[4]; o1.y = o[5]; o1.z = o[6]; o1.w = o[7];
            float* cp = C + (size_t)gr * 256 + c0;
            *(float4*)cp = o0;
            *(float4*)(cp + 4) = o1;
        }
    }
}

// ---------------- per-graph mean readout ----------------

__global__ void gcount_kernel(const int* __restrict__ gids, int* __restrict__ gcnt, int N) {
    int n = blockIdx.x * blockDim.x + threadIdx.x;
    if (n < N) atomicAdd(&gcnt[gids[n]], 1);
}

#define RCHUNK 512
__global__ void readout_kernel(const float* __restrict__ h2, const int* __restrict__ gids,
                               float* __restrict__ gsum, int N) {
    __shared__ int sg[RCHUNK];
    int n0 = blockIdx.x * RCHUNK;
    int tid = threadIdx.x;  // 256 = feature
    int cnt = N - n0; if (cnt > RCHUNK) cnt = RCHUNK;
    if (cnt <= 0) return;
    for (int i = tid; i < cnt; i += 256) sg[i] = gids[n0 + i];
    __syncthreads();
    int curg = sg[0];
    float acc = 0.0f;
    for (int i = 0; i < cnt; ++i) {
        int g = sg[i];
        if (g != curg) {
            atomicAdd(&gsum[curg * 256 + tid], acc);
            acc = 0.0f;
            curg = g;
        }
        acc += h2[(size_t)(n0 + i) * 256 + tid];
    }
    atomicAdd(&gsum[curg * 256 + tid], acc);
}

// ---------------- MLP head: out[g] = (gsum[g]/cnt @ Wr1 + br1) @ Wr2 + br2 ----------------

__global__ void final_kernel(const float* __restrict__ gsum, const int* __restrict__ gcnt,
                             const float* __restrict__ Wr1, const float* __restrict__ br1,
                             const float* __restrict__ Wr2, const float* __restrict__ br2,
                             float* __restrict__ out) {
    int g = blockIdx.x;
    int j = threadIdx.x;  // 128
    int c = gcnt[g];
    float invc = 1.0f / (float)(c > 0 ? c : 1);
    const float* gs = gsum + g * 256;
    float acc = br1[j];
    for (int k = 0; k < 256; ++k)
        acc += (gs[k] * invc) * Wr1[k * 128 + j];
    float p = acc * Wr2[j];
    #pragma unroll
    for (int d = 32; d > 0; d >>= 1) p += __shfl_down(p, d, 64);
    __shared__ float ws2[2];
    if ((j & 63) == 0) ws2[j >> 6] = p;
    __syncthreads();
    if (j == 0) out[g] = ws2[0] + ws2[1] + br2[0];
}

// ---------------- launch ----------------

extern "C" void kernel_launch(void* const* d_in, const int* in_sizes, int n_in,
                              void* d_out, int out_size, void* d_ws, size_t ws_size,
                              hipStream_t stream) {
    const float* h    = (const float*)d_in[0];
    const int*   src  = (const int*)d_in[1];
    const int*   dst  = (const int*)d_in[2];
    const int*   gids = (const int*)d_in[3];
    const float* W1   = (const float*)d_in[4];
    const float* b1   = (const float*)d_in[5];
    const float* W2   = (const float*)d_in[6];
    const float* b2   = (const float*)d_in[7];
    const float* Wr1  = (const float*)d_in[8];
    const float* br1  = (const float*)d_in[9];
    const float* Wr2  = (const float*)d_in[10];
    const float* br2  = (const float*)d_in[11];

    int N = in_sizes[0] / 128;
    int E = in_sizes[1];

    // workspace layout
    char* w = (char*)d_ws;
    float* bufA = (float*)w;            w += (size_t)N * 256 * sizeof(float);
    float* bufB = (float*)w;            w += (size_t)N * 256 * sizeof(float);
    int* cnt    = (int*)w;              w += (size_t)N * sizeof(int);
    int* offs   = (int*)w;              w += (size_t)(N + 1) * sizeof(int);
    int* cur    = (int*)w;              w += (size_t)N * sizeof(int);
    int* eidx   = (int*)w;              w += (size_t)E * sizeof(int);
    float* gsum = (float*)w;            w += (size_t)NUM_GRAPHS * 256 * sizeof(float);
    int* gcnt   = (int*)w;              w += (size_t)NUM_GRAPHS * sizeof(int);

    hipMemsetAsync(cnt, 0, (size_t)N * sizeof(int), stream);
    hipMemsetAsync(cur, 0, (size_t)N * sizeof(int), stream);
    hipMemsetAsync(gsum, 0, (size_t)NUM_GRAPHS * 256 * sizeof(float), stream);
    hipMemsetAsync(gcnt, 0, (size_t)NUM_GRAPHS * sizeof(int), stream);

    count_kernel<<<(E + 255) / 256, 256, 0, stream>>>(dst, cnt, E);
    scan_kernel<<<1, 1024, 0, stream>>>(cnt, offs, N);
    scatter_kernel<<<(E + 255) / 256, 256, 0, stream>>>(src, dst, offs, cur, eidx, E);

    // layer 1: aggregate h (D=128) -> bufA; gemm 128->256 -> bufB
    agg_mean_kernel<128><<<(N + 3) / 4, 256, 0, stream>>>(h, offs, eidx, bufA, N);
    gemm_relu_kernel<128><<<(N + 63) / 64, 256, 0, stream>>>(bufA, W1, b1, bufB, N);

    // layer 2: aggregate bufB (D=256) -> bufA; gemm 256->256 -> bufB
    agg_mean_kernel<256><<<(N + 3) / 4, 256, 0, stream>>>(bufB, offs, eidx, bufA, N);
    gemm_relu_kernel<256><<<(N + 63) / 64, 256, 0, stream>>>(bufA, W2, b2, bufB, N);

    // readout
    gcount_kernel<<<(N + 255) / 256, 256, 0, stream>>>(gids, gcnt, N);
    readout_kernel<<<(N + RCHUNK - 1) / RCHUNK, 256, 0, stream>>>(bufB, gids, gsum, N);
    final_kernel<<<NUM_GRAPHS, 128, 0, stream>>>(gsum, gcnt, Wr1, br1, Wr2, br2, (float*)d_out);
}

// Round 2
// 610.066 us; speedup vs baseline: 1.3254x; 1.3254x over previous
//
#include <hip/hip_runtime.h>

// GCN regressor: 2x (mean-aggregate + linear+ReLU) + per-graph mean + MLP head.
// N=50000 nodes, E=800000 edges, D_IN=128, H1=256, H2=128, G=256. All fp32.

#define NUM_GRAPHS 256

// ---------------- CSR build ----------------

__global__ void count_kernel(const int* __restrict__ dst, int* __restrict__ cnt, int E) {
    int e = blockIdx.x * blockDim.x + threadIdx.x;
    if (e < E) atomicAdd(&cnt[dst[e]], 1);
}

// Hierarchical scan: (1) per-block exclusive scan of 1024 elems + block totals,
// (2) single-wave exclusive scan of block totals (<=64 blocks), (3) add.

__global__ void scan1_kernel(const int* __restrict__ cnt, int* __restrict__ offs,
                             int* __restrict__ part, int N) {
    __shared__ int wsum[16];
    int tid = threadIdx.x;
    int lane = tid & 63;
    int wid = tid >> 6;
    int i = blockIdx.x * 1024 + tid;
    int v = (i < N) ? cnt[i] : 0;
    int x = v;
    #pragma unroll
    for (int d = 1; d < 64; d <<= 1) {
        int y = __shfl_up(x, d, 64);
        if (lane >= d) x += y;
    }
    if (lane == 63) wsum[wid] = x;
    __syncthreads();
    if (wid == 0) {
        int s = (lane < 16) ? wsum[lane] : 0;
        #pragma unroll
        for (int d = 1; d < 16; d <<= 1) {
            int y = __shfl_up(s, d, 64);
            if (lane >= d) s += y;
        }
        if (lane < 16) wsum[lane] = s;
    }
    __syncthreads();
    int wbase = (wid > 0) ? wsum[wid - 1] : 0;
    if (i < N) offs[i] = wbase + x - v;  // block-local exclusive
    if (tid == 1023) part[blockIdx.x] = wbase + x;  // block total
}

__global__ void scan2_kernel(int* __restrict__ part, int* __restrict__ offs, int N, int P) {
    int lane = threadIdx.x;  // 64 threads, P <= 64
    int v = (lane < P) ? part[lane] : 0;
    int x = v;
    #pragma unroll
    for (int d = 1; d < 64; d <<= 1) {
        int y = __shfl_up(x, d, 64);
        if (lane >= d) x += y;
    }
    if (lane < P) part[lane] = x - v;  // exclusive
    if (lane == 63) offs[N] = x;       // grand total
}

__global__ void scan3_kernel(int* __restrict__ offs, const int* __restrict__ part, int N) {
    int i = blockIdx.x * 1024 + threadIdx.x;
    if (i < N) offs[i] += part[blockIdx.x];
}

__global__ void scatter_kernel(const int* __restrict__ src, const int* __restrict__ dst,
                               const int* __restrict__ offs, int* __restrict__ cur,
                               int* __restrict__ eidx, int E) {
    int e = blockIdx.x * blockDim.x + threadIdx.x;
    if (e < E) {
        int d = dst[e];
        int p = offs[d] + atomicAdd(&cur[d], 1);
        eidx[p] = src[e];
    }
}

// ---------------- mean aggregation: one wave per dst node, edge loop unrolled 4x ----------------

template <int D>
__global__ void agg_mean_kernel(const float* __restrict__ feat, const int* __restrict__ offs,
                                const int* __restrict__ eidx, float* __restrict__ out, int N) {
    constexpr int VPL = D / 64;  // floats per lane (2 or 4)
    int wave = blockIdx.x * (blockDim.x >> 6) + (threadIdx.x >> 6);
    int lane = threadIdx.x & 63;
    if (wave >= N) return;
    int beg = offs[wave], end = offs[wave + 1];
    float acc[VPL];
    #pragma unroll
    for (int i = 0; i < VPL; ++i) acc[i] = 0.0f;

    int j = beg;
    for (; j + 4 <= end; j += 4) {
        int s0 = eidx[j], s1 = eidx[j + 1], s2 = eidx[j + 2], s3 = eidx[j + 3];
        if constexpr (VPL == 2) {
            float2 v0 = *(const float2*)(feat + (size_t)s0 * D + lane * 2);
            float2 v1 = *(const float2*)(feat + (size_t)s1 * D + lane * 2);
            float2 v2 = *(const float2*)(feat + (size_t)s2 * D + lane * 2);
            float2 v3 = *(const float2*)(feat + (size_t)s3 * D + lane * 2);
            acc[0] += v0.x + v1.x + v2.x + v3.x;
            acc[1] += v0.y + v1.y + v2.y + v3.y;
        } else {
            float4 v0 = *(const float4*)(feat + (size_t)s0 * D + lane * 4);
            float4 v1 = *(const float4*)(feat + (size_t)s1 * D + lane * 4);
            float4 v2 = *(const float4*)(feat + (size_t)s2 * D + lane * 4);
            float4 v3 = *(const float4*)(feat + (size_t)s3 * D + lane * 4);
            acc[0] += v0.x + v1.x + v2.x + v3.x;
            acc[1] += v0.y + v1.y + v2.y + v3.y;
            acc[2] += v0.z + v1.z + v2.z + v3.z;
            acc[3] += v0.w + v1.w + v2.w + v3.w;
        }
    }
    for (; j < end; ++j) {
        int s = eidx[j];
        if constexpr (VPL == 2) {
            float2 v = *(const float2*)(feat + (size_t)s * D + lane * 2);
            acc[0] += v.x; acc[1] += v.y;
        } else {
            float4 v = *(const float4*)(feat + (size_t)s * D + lane * 4);
            acc[0] += v.x; acc[1] += v.y; acc[2] += v.z; acc[3] += v.w;
        }
    }

    int deg = end - beg;
    float invd = 1.0f / (float)(deg > 0 ? deg : 1);
    float* orow = out + (size_t)wave * D + lane * VPL;
    if constexpr (VPL == 2) {
        float2 o; o.x = acc[0] * invd; o.y = acc[1] * invd;
        *(float2*)orow = o;
    } else {
        float4 o; o.x = acc[0] * invd; o.y = acc[1] * invd; o.z = acc[2] * invd; o.w = acc[3] * invd;
        *(float4*)orow = o;
    }
}

// ---------------- fp32 GEMM + bias + ReLU: C[N,256] = relu(A[N,K] @ W[K,256] + b) ----------------

template <int K>
__launch_bounds__(256)
__global__ void gemm_relu_kernel(const float* __restrict__ A, const float* __restrict__ W,
                                 const float* __restrict__ bias, float* __restrict__ C, int N) {
    constexpr int LDA = 68;
    __shared__ float AsT[128 * LDA];  // 34816 B

    int tid = threadIdx.x;
    int tc = tid & 31;   // thread-col: 32 * 8 = 256 cols
    int tr = tid >> 5;   // thread-row: 8 * 8 = 64 rows
    int c0 = tc * 8;
    int rowBase = blockIdx.x * 64;

    float acc[8][8];
    #pragma unroll
    for (int i = 0; i < 8; ++i)
        #pragma unroll
        for (int j = 0; j < 8; ++j) acc[i][j] = 0.0f;

    for (int kc = 0; kc < K; kc += 128) {
        for (int t = tid; t < 128 * 16; t += 256) {
            int k = t & 127;
            int rb = (t >> 7) * 4;
            float v[4];
            #pragma unroll
            for (int j = 0; j < 4; ++j) {
                int gr = rowBase + rb + j;
                v[j] = (gr < N) ? A[(size_t)gr * K + kc + k] : 0.0f;
            }
            float4 pv; pv.x = v[0]; pv.y = v[1]; pv.z = v[2]; pv.w = v[3];
            *(float4*)&AsT[k * LDA + rb] = pv;
        }
        __syncthreads();

        for (int k = 0; k < 128; ++k) {
            float4 a0 = *(const float4*)&AsT[k * LDA + tr * 8];
            float4 a1 = *(const float4*)&AsT[k * LDA + tr * 8 + 4];
            const float* wr = W + (size_t)(kc + k) * 256 + c0;
            float4 w0 = *(const float4*)wr;
            float4 w1 = *(const float4*)(wr + 4);
            float a[8] = {a0.x, a0.y, a0.z, a0.w, a1.x, a1.y, a1.z, a1.w};
            float w[8] = {w0.x, w0.y, w0.z, w0.w, w1.x, w1.y, w1.z, w1.w};
            #pragma unroll
            for (int i = 0; i < 8; ++i)
                #pragma unroll
                for (int j = 0; j < 8; ++j)
                    acc[i][j] += a[i] * w[j];
        }
        __syncthreads();
    }

    float4 bv0 = *(const float4*)&bias[c0];
    float4 bv1 = *(const float4*)&bias[c0 + 4];
    float b[8] = {bv0.x, bv0.y, bv0.z, bv0.w, bv1.x, bv1.y, bv1.z, bv1.w};
    #pragma unroll
    for (int i = 0; i < 8; ++i) {
        int gr = rowBase + tr * 8 + i;
        if (gr < N) {
            float o[8];
            #pragma unroll
            for (int j = 0; j < 8; ++j) o[j] = fmaxf(acc[i][j] + b[j], 0.0f);
            float4 o0; o0.x = o[0]; o0.y = o[1]; o0.z = o[2]; o0.w = o[3];
            float4 o1; o1.x = o[4]; o1.y = o[5]; o1.z = o[6]; o1.w = o[7];
            float* cp = C + (size_t)gr * 256 + c0;
            *(float4*)cp = o0;
            *(float4*)(cp + 4) = o1;
        }
    }
}

// ---------------- per-graph mean readout ----------------

__global__ void gcount_kernel(const int* __restrict__ gids, int* __restrict__ gcnt, int N) {
    int n = blockIdx.x * blockDim.x + threadIdx.x;
    if (n < N) atomicAdd(&gcnt[gids[n]], 1);
}

// 64 nodes per block; 8-row register batches so loads pipeline.
#define RCHUNK 64
__global__ void readout_kernel(const float* __restrict__ h2, const int* __restrict__ gids,
                               float* __restrict__ gsum, int N) {
    __shared__ int sg[RCHUNK];
    int n0 = blockIdx.x * RCHUNK;
    int tid = threadIdx.x;  // 256 = feature
    int cnt = N - n0; if (cnt > RCHUNK) cnt = RCHUNK;
    if (cnt <= 0) return;
    for (int i = tid; i < cnt; i += 256) sg[i] = gids[n0 + i];
    __syncthreads();
    int curg = sg[0];
    float acc = 0.0f;
    int i = 0;
    for (; i + 8 <= cnt; i += 8) {
        float v[8];
        #pragma unroll
        for (int u = 0; u < 8; ++u)
            v[u] = h2[(size_t)(n0 + i + u) * 256 + tid];
        #pragma unroll
        for (int u = 0; u < 8; ++u) {
            int g = sg[i + u];
            if (g != curg) {
                atomicAdd(&gsum[curg * 256 + tid], acc);
                acc = 0.0f;
                curg = g;
            }
            acc += v[u];
        }
    }
    for (; i < cnt; ++i) {
        int g = sg[i];
        if (g != curg) {
            atomicAdd(&gsum[curg * 256 + tid], acc);
            acc = 0.0f;
            curg = g;
        }
        acc += h2[(size_t)(n0 + i) * 256 + tid];
    }
    atomicAdd(&gsum[curg * 256 + tid], acc);
}

// ---------------- MLP head ----------------

__global__ void final_kernel(const float* __restrict__ gsum, const int* __restrict__ gcnt,
                             const float* __restrict__ Wr1, const float* __restrict__ br1,
                             const float* __restrict__ Wr2, const float* __restrict__ br2,
                             float* __restrict__ out) {
    int g = blockIdx.x;
    int j = threadIdx.x;  // 128
    int c = gcnt[g];
    float invc = 1.0f / (float)(c > 0 ? c : 1);
    const float* gs = gsum + g * 256;
    float acc = br1[j];
    for (int k = 0; k < 256; ++k)
        acc += (gs[k] * invc) * Wr1[k * 128 + j];
    float p = acc * Wr2[j];
    #pragma unroll
    for (int d = 32; d > 0; d >>= 1) p += __shfl_down(p, d, 64);
    __shared__ float ws2[2];
    if ((j & 63) == 0) ws2[j >> 6] = p;
    __syncthreads();
    if (j == 0) out[g] = ws2[0] + ws2[1] + br2[0];
}

// ---------------- launch ----------------

extern "C" void kernel_launch(void* const* d_in, const int* in_sizes, int n_in,
                              void* d_out, int out_size, void* d_ws, size_t ws_size,
                              hipStream_t stream) {
    const float* h    = (const float*)d_in[0];
    const int*   src  = (const int*)d_in[1];
    const int*   dst  = (const int*)d_in[2];
    const int*   gids = (const int*)d_in[3];
    const float* W1   = (const float*)d_in[4];
    const float* b1   = (const float*)d_in[5];
    const float* W2   = (const float*)d_in[6];
    const float* b2   = (const float*)d_in[7];
    const float* Wr1  = (const float*)d_in[8];
    const float* br1  = (const float*)d_in[9];
    const float* Wr2  = (const float*)d_in[10];
    const float* br2  = (const float*)d_in[11];

    int N = in_sizes[0] / 128;
    int E = in_sizes[1];
    int nScanBlocks = (N + 1023) / 1024;  // 49 for N=50000, must be <= 64

    // workspace layout
    char* w = (char*)d_ws;
    float* bufA = (float*)w;            w += (size_t)N * 256 * sizeof(float);
    float* bufB = (float*)w;            w += (size_t)N * 256 * sizeof(float);
    int* cnt    = (int*)w;              w += (size_t)N * sizeof(int);
    int* offs   = (int*)w;              w += (size_t)(N + 1) * sizeof(int);
    int* cur    = (int*)w;              w += (size_t)N * sizeof(int);
    int* eidx   = (int*)w;              w += (size_t)E * sizeof(int);
    int* part   = (int*)w;              w += 64 * sizeof(int);
    float* gsum = (float*)w;            w += (size_t)NUM_GRAPHS * 256 * sizeof(float);
    int* gcnt   = (int*)w;              w += (size_t)NUM_GRAPHS * sizeof(int);

    hipMemsetAsync(cnt, 0, (size_t)N * sizeof(int), stream);
    hipMemsetAsync(cur, 0, (size_t)N * sizeof(int), stream);
    hipMemsetAsync(gsum, 0, (size_t)NUM_GRAPHS * 256 * sizeof(float), stream);
    hipMemsetAsync(gcnt, 0, (size_t)NUM_GRAPHS * sizeof(int), stream);

    count_kernel<<<(E + 255) / 256, 256, 0, stream>>>(dst, cnt, E);
    scan1_kernel<<<nScanBlocks, 1024, 0, stream>>>(cnt, offs, part, N);
    scan2_kernel<<<1, 64, 0, stream>>>(part, offs, N, nScanBlocks);
    scan3_kernel<<<nScanBlocks, 1024, 0, stream>>>(offs, part, N);
    scatter_kernel<<<(E + 255) / 256, 256, 0, stream>>>(src, dst, offs, cur, eidx, E);

    // layer 1: aggregate h (D=128) -> bufA; gemm 128->256 -> bufB
    agg_mean_kernel<128><<<(N + 3) / 4, 256, 0, stream>>>(h, offs, eidx, bufA, N);
    gemm_relu_kernel<128><<<(N + 63) / 64, 256, 0, stream>>>(bufA, W1, b1, bufB, N);

    // layer 2: aggregate bufB (D=256) -> bufA; gemm 256->256 -> bufB
    agg_mean_kernel<256><<<(N + 3) / 4, 256, 0, stream>>>(bufB, offs, eidx, bufA, N);
    gemm_relu_kernel<256><<<(N + 63) / 64, 256, 0, stream>>>(bufA, W2, b2, bufB, N);

    // readout
    gcount_kernel<<<(N + 255) / 256, 256, 0, stream>>>(gids, gcnt, N);
    readout_kernel<<<(N + RCHUNK - 1) / RCHUNK, 256, 0, stream>>>(bufB, gids, gsum, N);
    final_kernel<<<NUM_GRAPHS, 128, 0, stream>>>(gsum, gcnt, Wr1, br1, Wr2, br2, (float*)d_out);
}

// Round 3
// 536.090 us; speedup vs baseline: 1.5083x; 1.1380x over previous
//
#include <hip/hip_runtime.h>

// GCN regressor: 2x (mean-aggregate + linear+ReLU) + per-graph mean + MLP head.
// N=50000 nodes, E=800000 edges, D_IN=128, H1=256, H2=128, G=256.
// R3: gather tables stored bf16 (halve gather traffic), accumulate fp32.

#define NUM_GRAPHS 256

__device__ inline unsigned short f2bf(float f) {  // round-to-nearest-even
    unsigned u = __float_as_uint(f);
    return (unsigned short)((u + 0x7fff + ((u >> 16) & 1)) >> 16);
}
__device__ inline float bflo(unsigned u) { return __uint_as_float(u << 16); }
__device__ inline float bfhi(unsigned u) { return __uint_as_float(u & 0xffff0000u); }

// ---------------- CSR build ----------------

__global__ void count_kernel(const int* __restrict__ dst, int* __restrict__ cnt, int E) {
    int e = blockIdx.x * blockDim.x + threadIdx.x;
    if (e < E) atomicAdd(&cnt[dst[e]], 1);
}

__global__ void scan1_kernel(const int* __restrict__ cnt, int* __restrict__ offs,
                             int* __restrict__ part, int N) {
    __shared__ int wsum[16];
    int tid = threadIdx.x;
    int lane = tid & 63;
    int wid = tid >> 6;
    int i = blockIdx.x * 1024 + tid;
    int v = (i < N) ? cnt[i] : 0;
    int x = v;
    #pragma unroll
    for (int d = 1; d < 64; d <<= 1) {
        int y = __shfl_up(x, d, 64);
        if (lane >= d) x += y;
    }
    if (lane == 63) wsum[wid] = x;
    __syncthreads();
    if (wid == 0) {
        int s = (lane < 16) ? wsum[lane] : 0;
        #pragma unroll
        for (int d = 1; d < 16; d <<= 1) {
            int y = __shfl_up(s, d, 64);
            if (lane >= d) s += y;
        }
        if (lane < 16) wsum[lane] = s;
    }
    __syncthreads();
    int wbase = (wid > 0) ? wsum[wid - 1] : 0;
    if (i < N) offs[i] = wbase + x - v;
    if (tid == 1023) part[blockIdx.x] = wbase + x;
}

__global__ void scan2_kernel(int* __restrict__ part, int* __restrict__ offs, int N, int P) {
    int lane = threadIdx.x;  // 64 threads, P <= 64
    int v = (lane < P) ? part[lane] : 0;
    int x = v;
    #pragma unroll
    for (int d = 1; d < 64; d <<= 1) {
        int y = __shfl_up(x, d, 64);
        if (lane >= d) x += y;
    }
    if (lane < P) part[lane] = x - v;
    if (lane == 63) offs[N] = x;
}

__global__ void scan3_kernel(int* __restrict__ offs, const int* __restrict__ part, int N) {
    int i = blockIdx.x * 1024 + threadIdx.x;
    if (i < N) offs[i] += part[blockIdx.x];
}

__global__ void scatter_kernel(const int* __restrict__ src, const int* __restrict__ dst,
                               const int* __restrict__ offs, int* __restrict__ cur,
                               int* __restrict__ eidx, int E) {
    int e = blockIdx.x * blockDim.x + threadIdx.x;
    if (e < E) {
        int d = dst[e];
        int p = offs[d] + atomicAdd(&cur[d], 1);
        eidx[p] = src[e];
    }
}

// ---------------- fp32 -> bf16 cast (for the layer-1 gather table) ----------------

__global__ void cast_bf16_kernel(const float* __restrict__ in, unsigned short* __restrict__ out,
                                 int total4) {
    int i = blockIdx.x * blockDim.x + threadIdx.x;  // one float4 per thread
    if (i < total4) {
        float4 v = *(const float4*)(in + (size_t)i * 4);
        ushort4 o;
        o.x = f2bf(v.x); o.y = f2bf(v.y); o.z = f2bf(v.z); o.w = f2bf(v.w);
        *(ushort4*)(out + (size_t)i * 4) = o;
    }
}

// ---------------- mean aggregation: one wave per dst node, bf16 gather, fp32 accum ----------------
// D=128: lane covers 2 elems (uint); D=256: 4 elems (uint2). Edge loop unrolled 8x.

template <int D>
__global__ void agg_mean_bf16_kernel(const unsigned short* __restrict__ feat,
                                     const int* __restrict__ offs,
                                     const int* __restrict__ eidx,
                                     float* __restrict__ out, int N) {
    constexpr int VPL = D / 64;  // 2 or 4
    int wave = blockIdx.x * (blockDim.x >> 6) + (threadIdx.x >> 6);
    int lane = threadIdx.x & 63;
    if (wave >= N) return;
    int beg = offs[wave], end = offs[wave + 1];
    float acc[VPL];
    #pragma unroll
    for (int i = 0; i < VPL; ++i) acc[i] = 0.0f;

    int j = beg;
    for (; j + 8 <= end; j += 8) {
        int s[8];
        #pragma unroll
        for (int u = 0; u < 8; ++u) s[u] = eidx[j + u];
        if constexpr (VPL == 2) {
            unsigned v[8];
            #pragma unroll
            for (int u = 0; u < 8; ++u)
                v[u] = *(const unsigned*)(feat + (size_t)s[u] * D + lane * 2);
            #pragma unroll
            for (int u = 0; u < 8; ++u) { acc[0] += bflo(v[u]); acc[1] += bfhi(v[u]); }
        } else {
            uint2 v[8];
            #pragma unroll
            for (int u = 0; u < 8; ++u)
                v[u] = *(const uint2*)(feat + (size_t)s[u] * D + lane * 4);
            #pragma unroll
            for (int u = 0; u < 8; ++u) {
                acc[0] += bflo(v[u].x); acc[1] += bfhi(v[u].x);
                acc[2] += bflo(v[u].y); acc[3] += bfhi(v[u].y);
            }
        }
    }
    for (; j < end; ++j) {
        int s = eidx[j];
        if constexpr (VPL == 2) {
            unsigned v = *(const unsigned*)(feat + (size_t)s * D + lane * 2);
            acc[0] += bflo(v); acc[1] += bfhi(v);
        } else {
            uint2 v = *(const uint2*)(feat + (size_t)s * D + lane * 4);
            acc[0] += bflo(v.x); acc[1] += bfhi(v.x);
            acc[2] += bflo(v.y); acc[3] += bfhi(v.y);
        }
    }

    int deg = end - beg;
    float invd = 1.0f / (float)(deg > 0 ? deg : 1);
    float* orow = out + (size_t)wave * D + lane * VPL;
    if constexpr (VPL == 2) {
        float2 o; o.x = acc[0] * invd; o.y = acc[1] * invd;
        *(float2*)orow = o;
    } else {
        float4 o; o.x = acc[0] * invd; o.y = acc[1] * invd; o.z = acc[2] * invd; o.w = acc[3] * invd;
        *(float4*)orow = o;
    }
}

// ---------------- fp32 GEMM + bias + ReLU: C[N,256] = relu(A[N,K] @ W[K,256] + b) ----------------
// OBF16: write output as bf16 (layer-1 output feeds only the bf16 gather).

template <int K, bool OBF16>
__launch_bounds__(256)
__global__ void gemm_relu_kernel(const float* __restrict__ A, const float* __restrict__ W,
                                 const float* __restrict__ bias, float* __restrict__ Cf,
                                 unsigned short* __restrict__ Cb, int N) {
    constexpr int LDA = 68;
    __shared__ float AsT[128 * LDA];

    int tid = threadIdx.x;
    int tc = tid & 31;
    int tr = tid >> 5;
    int c0 = tc * 8;
    int rowBase = blockIdx.x * 64;

    float acc[8][8];
    #pragma unroll
    for (int i = 0; i < 8; ++i)
        #pragma unroll
        for (int j = 0; j < 8; ++j) acc[i][j] = 0.0f;

    for (int kc = 0; kc < K; kc += 128) {
        for (int t = tid; t < 128 * 16; t += 256) {
            int k = t & 127;
            int rb = (t >> 7) * 4;
            float v[4];
            #pragma unroll
            for (int j = 0; j < 4; ++j) {
                int gr = rowBase + rb + j;
                v[j] = (gr < N) ? A[(size_t)gr * K + kc + k] : 0.0f;
            }
            float4 pv; pv.x = v[0]; pv.y = v[1]; pv.z = v[2]; pv.w = v[3];
            *(float4*)&AsT[k * LDA + rb] = pv;
        }
        __syncthreads();

        for (int k = 0; k < 128; ++k) {
            float4 a0 = *(const float4*)&AsT[k * LDA + tr * 8];
            float4 a1 = *(const float4*)&AsT[k * LDA + tr * 8 + 4];
            const float* wr = W + (size_t)(kc + k) * 256 + c0;
            float4 w0 = *(const float4*)wr;
            float4 w1 = *(const float4*)(wr + 4);
            float a[8] = {a0.x, a0.y, a0.z, a0.w, a1.x, a1.y, a1.z, a1.w};
            float w[8] = {w0.x, w0.y, w0.z, w0.w, w1.x, w1.y, w1.z, w1.w};
            #pragma unroll
            for (int i = 0; i < 8; ++i)
                #pragma unroll
                for (int j = 0; j < 8; ++j)
                    acc[i][j] += a[i] * w[j];
        }
        __syncthreads();
    }

    float4 bv0 = *(const float4*)&bias[c0];
    float4 bv1 = *(const float4*)&bias[c0 + 4];
    float b[8] = {bv0.x, bv0.y, bv0.z, bv0.w, bv1.x, bv1.y, bv1.z, bv1.w};
    #pragma unroll
    for (int i = 0; i < 8; ++i) {
        int gr = rowBase + tr * 8 + i;
        if (gr < N) {
            float o[8];
            #pragma unroll
            for (int j = 0; j < 8; ++j) o[j] = fmaxf(acc[i][j] + b[j], 0.0f);
            if constexpr (OBF16) {
                ushort4 p0, p1;
                p0.x = f2bf(o[0]); p0.y = f2bf(o[1]); p0.z = f2bf(o[2]); p0.w = f2bf(o[3]);
                p1.x = f2bf(o[4]); p1.y = f2bf(o[5]); p1.z = f2bf(o[6]); p1.w = f2bf(o[7]);
                unsigned short* cp = Cb + (size_t)gr * 256 + c0;
                *(ushort4*)cp = p0;
                *(ushort4*)(cp + 4) = p1;
            } else {
                float4 o0; o0.x = o[0]; o0.y = o[1]; o0.z = o[2]; o0.w = o[3];
                float4 o1; o1.x = o[4]; o1.y = o[5]; o1.z = o[6]; o1.w = o[7];
                float* cp = Cf + (size_t)gr * 256 + c0;
                *(float4*)cp = o0;
                *(float4*)(cp + 4) = o1;
            }
        }
    }
}

// ---------------- per-graph mean readout ----------------

__global__ void gcount_kernel(const int* __restrict__ gids, int* __restrict__ gcnt, int N) {
    int n = blockIdx.x * blockDim.x + threadIdx.x;
    if (n < N) atomicAdd(&gcnt[gids[n]], 1);
}

#define RCHUNK 64
__global__ void readout_kernel(const float* __restrict__ h2, const int* __restrict__ gids,
                               float* __restrict__ gsum, int N) {
    __shared__ int sg[RCHUNK];
    int n0 = blockIdx.x * RCHUNK;
    int tid = threadIdx.x;  // 256 = feature
    int cnt = N - n0; if (cnt > RCHUNK) cnt = RCHUNK;
    if (cnt <= 0) return;
    for (int i = tid; i < cnt; i += 256) sg[i] = gids[n0 + i];
    __syncthreads();
    int curg = sg[0];
    float acc = 0.0f;
    int i = 0;
    for (; i + 8 <= cnt; i += 8) {
        float v[8];
        #pragma unroll
        for (int u = 0; u < 8; ++u)
            v[u] = h2[(size_t)(n0 + i + u) * 256 + tid];
        #pragma unroll
        for (int u = 0; u < 8; ++u) {
            int g = sg[i + u];
            if (g != curg) {
                atomicAdd(&gsum[curg * 256 + tid], acc);
                acc = 0.0f;
                curg = g;
            }
            acc += v[u];
        }
    }
    for (; i < cnt; ++i) {
        int g = sg[i];
        if (g != curg) {
            atomicAdd(&gsum[curg * 256 + tid], acc);
            acc = 0.0f;
            curg = g;
        }
        acc += h2[(size_t)(n0 + i) * 256 + tid];
    }
    atomicAdd(&gsum[curg * 256 + tid], acc);
}

// ---------------- MLP head ----------------

__global__ void final_kernel(const float* __restrict__ gsum, const int* __restrict__ gcnt,
                             const float* __restrict__ Wr1, const float* __restrict__ br1,
                             const float* __restrict__ Wr2, const float* __restrict__ br2,
                             float* __restrict__ out) {
    int g = blockIdx.x;
    int j = threadIdx.x;  // 128
    int c = gcnt[g];
    float invc = 1.0f / (float)(c > 0 ? c : 1);
    const float* gs = gsum + g * 256;
    float acc = br1[j];
    for (int k = 0; k < 256; ++k)
        acc += (gs[k] * invc) * Wr1[k * 128 + j];
    float p = acc * Wr2[j];
    #pragma unroll
    for (int d = 32; d > 0; d >>= 1) p += __shfl_down(p, d, 64);
    __shared__ float ws2[2];
    if ((j & 63) == 0) ws2[j >> 6] = p;
    __syncthreads();
    if (j == 0) out[g] = ws2[0] + ws2[1] + br2[0];
}

// ---------------- launch ----------------

extern "C" void kernel_launch(void* const* d_in, const int* in_sizes, int n_in,
                              void* d_out, int out_size, void* d_ws, size_t ws_size,
                              hipStream_t stream) {
    const float* h    = (const float*)d_in[0];
    const int*   src  = (const int*)d_in[1];
    const int*   dst  = (const int*)d_in[2];
    const int*   gids = (const int*)d_in[3];
    const float* W1   = (const float*)d_in[4];
    const float* b1   = (const float*)d_in[5];
    const float* W2   = (const float*)d_in[6];
    const float* b2   = (const float*)d_in[7];
    const float* Wr1  = (const float*)d_in[8];
    const float* br1  = (const float*)d_in[9];
    const float* Wr2  = (const float*)d_in[10];
    const float* br2  = (const float*)d_in[11];

    int N = in_sizes[0] / 128;
    int E = in_sizes[1];
    int nScanBlocks = (N + 1023) / 1024;  // 49 for N=50000, must be <= 64

    // workspace layout. Region R is time-shared: hb (cast of h, dead after agg1),
    // then h1b (bf16 h1, dead after agg2), then bufB (fp32 h2 for readout).
    char* w = (char*)d_ws;
    float* bufA = (float*)w;            w += (size_t)N * 256 * sizeof(float);
    char* region = w;                   w += (size_t)N * 256 * sizeof(float);
    unsigned short* hb  = (unsigned short*)region;
    unsigned short* h1b = (unsigned short*)region;
    float* bufB = (float*)region;
    int* cnt    = (int*)w;              w += (size_t)N * sizeof(int);
    int* offs   = (int*)w;              w += (size_t)(N + 1) * sizeof(int);
    int* cur    = (int*)w;              w += (size_t)N * sizeof(int);
    int* eidx   = (int*)w;              w += (size_t)E * sizeof(int);
    int* part   = (int*)w;              w += 64 * sizeof(int);
    float* gsum = (float*)w;            w += (size_t)NUM_GRAPHS * 256 * sizeof(float);
    int* gcnt   = (int*)w;              w += (size_t)NUM_GRAPHS * sizeof(int);

    hipMemsetAsync(cnt, 0, (size_t)N * sizeof(int), stream);
    hipMemsetAsync(cur, 0, (size_t)N * sizeof(int), stream);
    hipMemsetAsync(gsum, 0, (size_t)NUM_GRAPHS * 256 * sizeof(float), stream);
    hipMemsetAsync(gcnt, 0, (size_t)NUM_GRAPHS * sizeof(int), stream);

    count_kernel<<<(E + 255) / 256, 256, 0, stream>>>(dst, cnt, E);
    scan1_kernel<<<nScanBlocks, 1024, 0, stream>>>(cnt, offs, part, N);
    scan2_kernel<<<1, 64, 0, stream>>>(part, offs, N, nScanBlocks);
    scan3_kernel<<<nScanBlocks, 1024, 0, stream>>>(offs, part, N);
    scatter_kernel<<<(E + 255) / 256, 256, 0, stream>>>(src, dst, offs, cur, eidx, E);

    // layer 1: cast h->bf16; aggregate (D=128) -> bufA; gemm 128->256 -> h1b (bf16)
    cast_bf16_kernel<<<(N * 128 / 4 + 255) / 256, 256, 0, stream>>>(h, hb, N * 128 / 4);
    agg_mean_bf16_kernel<128><<<(N + 3) / 4, 256, 0, stream>>>(hb, offs, eidx, bufA, N);
    gemm_relu_kernel<128, true><<<(N + 63) / 64, 256, 0, stream>>>(bufA, W1, b1, nullptr, h1b, N);

    // layer 2: aggregate h1b (D=256) -> bufA; gemm 256->256 -> bufB (fp32)
    agg_mean_bf16_kernel<256><<<(N + 3) / 4, 256, 0, stream>>>(h1b, offs, eidx, bufA, N);
    gemm_relu_kernel<256, false><<<(N + 63) / 64, 256, 0, stream>>>(bufA, W2, b2, bufB, nullptr, N);

    // readout
    gcount_kernel<<<(N + 255) / 256, 256, 0, stream>>>(gids, gcnt, N);
    readout_kernel<<<(N + RCHUNK - 1) / RCHUNK, 256, 0, stream>>>(bufB, gids, gsum, N);
    final_kernel<<<NUM_GRAPHS, 128, 0, stream>>>(gsum, gcnt, Wr1, br1, Wr2, br2, (float*)d_out);
}

// Round 4
// 440.763 us; speedup vs baseline: 1.8345x; 1.2163x over previous
//
#include <hip/hip_runtime.h>

// GCN regressor: 2x (mean-aggregate + linear+ReLU) + per-graph mean + MLP head.
// N=50000 nodes, E=800000 edges, D_IN=128, H1=256, H2=128, G=256.
// R4: GEMMs use bf16 MFMA (16x16x32); agg outputs stored bf16; weights
// transposed+cast to bf16 once per launch. fp32 accumulate everywhere.

#define NUM_GRAPHS 256

typedef __attribute__((ext_vector_type(8))) short bf16x8;
typedef __attribute__((ext_vector_type(4))) float f32x4;

__device__ inline unsigned short f2bf(float f) {  // round-to-nearest-even
    unsigned u = __float_as_uint(f);
    return (unsigned short)((u + 0x7fff + ((u >> 16) & 1)) >> 16);
}
__device__ inline float bflo(unsigned u) { return __uint_as_float(u << 16); }
__device__ inline float bfhi(unsigned u) { return __uint_as_float(u & 0xffff0000u); }

// ---------------- CSR build ----------------

__global__ void count_kernel(const int* __restrict__ dst, int* __restrict__ cnt, int E) {
    int e = blockIdx.x * blockDim.x + threadIdx.x;
    if (e < E) atomicAdd(&cnt[dst[e]], 1);
}

__global__ void scan1_kernel(const int* __restrict__ cnt, int* __restrict__ offs,
                             int* __restrict__ part, int N) {
    __shared__ int wsum[16];
    int tid = threadIdx.x;
    int lane = tid & 63;
    int wid = tid >> 6;
    int i = blockIdx.x * 1024 + tid;
    int v = (i < N) ? cnt[i] : 0;
    int x = v;
    #pragma unroll
    for (int d = 1; d < 64; d <<= 1) {
        int y = __shfl_up(x, d, 64);
        if (lane >= d) x += y;
    }
    if (lane == 63) wsum[wid] = x;
    __syncthreads();
    if (wid == 0) {
        int s = (lane < 16) ? wsum[lane] : 0;
        #pragma unroll
        for (int d = 1; d < 16; d <<= 1) {
            int y = __shfl_up(s, d, 64);
            if (lane >= d) s += y;
        }
        if (lane < 16) wsum[lane] = s;
    }
    __syncthreads();
    int wbase = (wid > 0) ? wsum[wid - 1] : 0;
    if (i < N) offs[i] = wbase + x - v;
    if (tid == 1023) part[blockIdx.x] = wbase + x;
}

__global__ void scan2_kernel(int* __restrict__ part, int* __restrict__ offs, int N, int P) {
    int lane = threadIdx.x;  // 64 threads, P <= 64
    int v = (lane < P) ? part[lane] : 0;
    int x = v;
    #pragma unroll
    for (int d = 1; d < 64; d <<= 1) {
        int y = __shfl_up(x, d, 64);
        if (lane >= d) x += y;
    }
    if (lane < P) part[lane] = x - v;
    if (lane == 63) offs[N] = x;
}

__global__ void scan3_kernel(int* __restrict__ offs, const int* __restrict__ part, int N) {
    int i = blockIdx.x * 1024 + threadIdx.x;
    if (i < N) offs[i] += part[blockIdx.x];
}

__global__ void scatter_kernel(const int* __restrict__ src, const int* __restrict__ dst,
                               const int* __restrict__ offs, int* __restrict__ cur,
                               int* __restrict__ eidx, int E) {
    int e = blockIdx.x * blockDim.x + threadIdx.x;
    if (e < E) {
        int d = dst[e];
        int p = offs[d] + atomicAdd(&cur[d], 1);
        eidx[p] = src[e];
    }
}

// ---------------- fp32 -> bf16 cast (layer-1 gather table) ----------------

__global__ void cast_bf16_kernel(const float* __restrict__ in, unsigned short* __restrict__ out,
                                 int total4) {
    int i = blockIdx.x * blockDim.x + threadIdx.x;
    if (i < total4) {
        float4 v = *(const float4*)(in + (size_t)i * 4);
        ushort4 o;
        o.x = f2bf(v.x); o.y = f2bf(v.y); o.z = f2bf(v.z); o.w = f2bf(v.w);
        *(ushort4*)(out + (size_t)i * 4) = o;
    }
}

// ---------------- weight transpose+cast: Wt[n][k] = bf16(W[k][n]), Ncols=256 ----------------

__global__ void transpose_cast_kernel(const float* __restrict__ W, unsigned short* __restrict__ Wt,
                                      int K) {
    __shared__ float tile[32][33];
    int k0 = blockIdx.x * 32;
    int n0 = blockIdx.y * 32;
    int tx = threadIdx.x & 31;
    int ty = threadIdx.x >> 5;  // 0..7
    #pragma unroll
    for (int i = 0; i < 4; ++i)
        tile[ty + i * 8][tx] = W[(size_t)(k0 + ty + i * 8) * 256 + n0 + tx];
    __syncthreads();
    #pragma unroll
    for (int i = 0; i < 4; ++i)
        Wt[(size_t)(n0 + ty + i * 8) * K + k0 + tx] = f2bf(tile[tx][ty + i * 8]);
}

// ---------------- mean aggregation: bf16 gather, fp32 accum, bf16 output ----------------

template <int D>
__global__ void agg_mean_bf16_kernel(const unsigned short* __restrict__ feat,
                                     const int* __restrict__ offs,
                                     const int* __restrict__ eidx,
                                     unsigned short* __restrict__ out, int N) {
    constexpr int VPL = D / 64;  // 2 or 4
    int wave = blockIdx.x * (blockDim.x >> 6) + (threadIdx.x >> 6);
    int lane = threadIdx.x & 63;
    if (wave >= N) return;
    int beg = offs[wave], end = offs[wave + 1];
    float acc[VPL];
    #pragma unroll
    for (int i = 0; i < VPL; ++i) acc[i] = 0.0f;

    int j = beg;
    for (; j + 8 <= end; j += 8) {
        int s[8];
        #pragma unroll
        for (int u = 0; u < 8; ++u) s[u] = eidx[j + u];
        if constexpr (VPL == 2) {
            unsigned v[8];
            #pragma unroll
            for (int u = 0; u < 8; ++u)
                v[u] = *(const unsigned*)(feat + (size_t)s[u] * D + lane * 2);
            #pragma unroll
            for (int u = 0; u < 8; ++u) { acc[0] += bflo(v[u]); acc[1] += bfhi(v[u]); }
        } else {
            uint2 v[8];
            #pragma unroll
            for (int u = 0; u < 8; ++u)
                v[u] = *(const uint2*)(feat + (size_t)s[u] * D + lane * 4);
            #pragma unroll
            for (int u = 0; u < 8; ++u) {
                acc[0] += bflo(v[u].x); acc[1] += bfhi(v[u].x);
                acc[2] += bflo(v[u].y); acc[3] += bfhi(v[u].y);
            }
        }
    }
    for (; j < end; ++j) {
        int s = eidx[j];
        if constexpr (VPL == 2) {
            unsigned v = *(const unsigned*)(feat + (size_t)s * D + lane * 2);
            acc[0] += bflo(v); acc[1] += bfhi(v);
        } else {
            uint2 v = *(const uint2*)(feat + (size_t)s * D + lane * 4);
            acc[0] += bflo(v.x); acc[1] += bfhi(v.x);
            acc[2] += bflo(v.y); acc[3] += bfhi(v.y);
        }
    }

    int deg = end - beg;
    float invd = 1.0f / (float)(deg > 0 ? deg : 1);
    unsigned short* orow = out + (size_t)wave * D + lane * VPL;
    if constexpr (VPL == 2) {
        ushort2 o; o.x = f2bf(acc[0] * invd); o.y = f2bf(acc[1] * invd);
        *(ushort2*)orow = o;
    } else {
        ushort4 o;
        o.x = f2bf(acc[0] * invd); o.y = f2bf(acc[1] * invd);
        o.z = f2bf(acc[2] * invd); o.w = f2bf(acc[3] * invd);
        *(ushort4*)orow = o;
    }
}

// ---------------- bf16 MFMA GEMM + bias + ReLU: C[N,256] = relu(A[N,K] @ W[K,256] + b) ----------------
// A: bf16 [N,K]; Wt: bf16 [256,K] (transposed). Block = 64 rows x 256 cols, 4 waves.
// Wave w covers cols w*64..w*64+63 as 4 col-tiles of 16; 4 row-tiles of 16; K in chunks of 32.
// LDS row stride 40 bf16: 16B aligned, <=2-way bank aliasing (free).

template <int K, bool OBF16>
__launch_bounds__(256)
__global__ void gemm_mfma_kernel(const unsigned short* __restrict__ A,
                                 const unsigned short* __restrict__ Wt,
                                 const float* __restrict__ bias,
                                 float* __restrict__ Cf, unsigned short* __restrict__ Cb,
                                 int N) {
    constexpr int LDS = 40;
    __shared__ unsigned short As[64 * LDS];    // 5.1 KB
    __shared__ unsigned short Bs[256 * LDS];   // 20.5 KB

    int tid = threadIdx.x;
    int wave = tid >> 6;
    int lane = tid & 63;
    int m = lane & 15;
    int q = lane >> 4;
    int rowBase = blockIdx.x * 64;

    f32x4 acc[4][4] = {};  // [rowtile][coltile]

    for (int kc = 0; kc < K; kc += 32) {
        {   // stage A: 64 rows x 32 k (one uint4 per thread)
            int r = tid >> 2;
            int seg = tid & 3;
            int gr = rowBase + r;
            uint4 v = make_uint4(0, 0, 0, 0);
            if (gr < N) v = *(const uint4*)(A + (size_t)gr * K + kc + seg * 8);
            *(uint4*)&As[r * LDS + seg * 8] = v;
        }
        #pragma unroll
        for (int it = 0; it < 4; ++it) {  // stage B: 256 n x 32 k
            int n = (tid >> 2) + it * 64;
            int seg = tid & 3;
            uint4 v = *(const uint4*)(Wt + (size_t)n * K + kc + seg * 8);
            *(uint4*)&Bs[n * LDS + seg * 8] = v;
        }
        __syncthreads();

        bf16x8 af[4], bfr[4];
        #pragma unroll
        for (int r = 0; r < 4; ++r)
            af[r] = *(const bf16x8*)&As[(r * 16 + m) * LDS + q * 8];
        #pragma unroll
        for (int c = 0; c < 4; ++c)
            bfr[c] = *(const bf16x8*)&Bs[(wave * 64 + c * 16 + m) * LDS + q * 8];
        #pragma unroll
        for (int r = 0; r < 4; ++r)
            #pragma unroll
            for (int c = 0; c < 4; ++c)
                acc[r][c] = __builtin_amdgcn_mfma_f32_16x16x32_bf16(af[r], bfr[c], acc[r][c], 0, 0, 0);
        __syncthreads();
    }

    // epilogue: C/D layout col=lane&15, row=(lane>>4)*4+reg
    #pragma unroll
    for (int c = 0; c < 4; ++c) {
        int col = wave * 64 + c * 16 + m;
        float bv = bias[col];
        #pragma unroll
        for (int r = 0; r < 4; ++r) {
            #pragma unroll
            for (int reg = 0; reg < 4; ++reg) {
                int grow = rowBase + r * 16 + q * 4 + reg;
                if (grow < N) {
                    float o = fmaxf(acc[r][c][reg] + bv, 0.0f);
                    if constexpr (OBF16) Cb[(size_t)grow * 256 + col] = f2bf(o);
                    else                 Cf[(size_t)grow * 256 + col] = o;
                }
            }
        }
    }
}

// ---------------- per-graph mean readout ----------------

__global__ void gcount_kernel(const int* __restrict__ gids, int* __restrict__ gcnt, int N) {
    int n = blockIdx.x * blockDim.x + threadIdx.x;
    if (n < N) atomicAdd(&gcnt[gids[n]], 1);
}

#define RCHUNK 64
__global__ void readout_kernel(const float* __restrict__ h2, const int* __restrict__ gids,
                               float* __restrict__ gsum, int N) {
    __shared__ int sg[RCHUNK];
    int n0 = blockIdx.x * RCHUNK;
    int tid = threadIdx.x;  // 256 = feature
    int cnt = N - n0; if (cnt > RCHUNK) cnt = RCHUNK;
    if (cnt <= 0) return;
    for (int i = tid; i < cnt; i += 256) sg[i] = gids[n0 + i];
    __syncthreads();
    int curg = sg[0];
    float acc = 0.0f;
    int i = 0;
    for (; i + 8 <= cnt; i += 8) {
        float v[8];
        #pragma unroll
        for (int u = 0; u < 8; ++u)
            v[u] = h2[(size_t)(n0 + i + u) * 256 + tid];
        #pragma unroll
        for (int u = 0; u < 8; ++u) {
            int g = sg[i + u];
            if (g != curg) {
                atomicAdd(&gsum[curg * 256 + tid], acc);
                acc = 0.0f;
                curg = g;
            }
            acc += v[u];
        }
    }
    for (; i < cnt; ++i) {
        int g = sg[i];
        if (g != curg) {
            atomicAdd(&gsum[curg * 256 + tid], acc);
            acc = 0.0f;
            curg = g;
        }
        acc += h2[(size_t)(n0 + i) * 256 + tid];
    }
    atomicAdd(&gsum[curg * 256 + tid], acc);
}

// ---------------- MLP head ----------------

__global__ void final_kernel(const float* __restrict__ gsum, const int* __restrict__ gcnt,
                             const float* __restrict__ Wr1, const float* __restrict__ br1,
                             const float* __restrict__ Wr2, const float* __restrict__ br2,
                             float* __restrict__ out) {
    int g = blockIdx.x;
    int j = threadIdx.x;  // 128
    int c = gcnt[g];
    float invc = 1.0f / (float)(c > 0 ? c : 1);
    const float* gs = gsum + g * 256;
    float acc = br1[j];
    for (int k = 0; k < 256; ++k)
        acc += (gs[k] * invc) * Wr1[k * 128 + j];
    float p = acc * Wr2[j];
    #pragma unroll
    for (int d = 32; d > 0; d >>= 1) p += __shfl_down(p, d, 64);
    __shared__ float ws2[2];
    if ((j & 63) == 0) ws2[j >> 6] = p;
    __syncthreads();
    if (j == 0) out[g] = ws2[0] + ws2[1] + br2[0];
}

// ---------------- launch ----------------

extern "C" void kernel_launch(void* const* d_in, const int* in_sizes, int n_in,
                              void* d_out, int out_size, void* d_ws, size_t ws_size,
                              hipStream_t stream) {
    const float* h    = (const float*)d_in[0];
    const int*   src  = (const int*)d_in[1];
    const int*   dst  = (const int*)d_in[2];
    const int*   gids = (const int*)d_in[3];
    const float* W1   = (const float*)d_in[4];
    const float* b1   = (const float*)d_in[5];
    const float* W2   = (const float*)d_in[6];
    const float* b2   = (const float*)d_in[7];
    const float* Wr1  = (const float*)d_in[8];
    const float* br1  = (const float*)d_in[9];
    const float* Wr2  = (const float*)d_in[10];
    const float* br2  = (const float*)d_in[11];

    int N = in_sizes[0] / 128;
    int E = in_sizes[1];
    int nScanBlocks = (N + 1023) / 1024;  // 49 for N=50000, must be <= 64

    // workspace. R1 (N*256*4 B) time-shares: hb (bf16 h, dead after agg1) ->
    // h1b (bf16 h1, dead after agg2) -> bufB (fp32 h2). R2 (N*256*2 B)
    // time-shares aggOut1 (bf16 [N,128]) -> aggOut2 (bf16 [N,256]).
    char* w = (char*)d_ws;
    char* R1 = w;                       w += (size_t)N * 256 * sizeof(float);
    char* R2 = w;                       w += (size_t)N * 256 * sizeof(unsigned short);
    unsigned short* hb   = (unsigned short*)R1;
    unsigned short* h1b  = (unsigned short*)R1;
    float*          bufB = (float*)R1;
    unsigned short* aggOut = (unsigned short*)R2;
    int* cnt    = (int*)w;              w += (size_t)N * sizeof(int);
    int* offs   = (int*)w;              w += (size_t)(N + 1) * sizeof(int);
    int* cur    = (int*)w;              w += (size_t)N * sizeof(int);
    int* eidx   = (int*)w;              w += (size_t)E * sizeof(int);
    int* part   = (int*)w;              w += 64 * sizeof(int);
    unsigned short* Wt1 = (unsigned short*)w;  w += 256 * 128 * sizeof(unsigned short);
    unsigned short* Wt2 = (unsigned short*)w;  w += 256 * 256 * sizeof(unsigned short);
    float* gsum = (float*)w;            w += (size_t)NUM_GRAPHS * 256 * sizeof(float);
    int* gcnt   = (int*)w;              w += (size_t)NUM_GRAPHS * sizeof(int);

    hipMemsetAsync(cnt, 0, (size_t)N * sizeof(int), stream);
    hipMemsetAsync(cur, 0, (size_t)N * sizeof(int), stream);
    hipMemsetAsync(gsum, 0, (size_t)NUM_GRAPHS * 256 * sizeof(float), stream);
    hipMemsetAsync(gcnt, 0, (size_t)NUM_GRAPHS * sizeof(int), stream);

    count_kernel<<<(E + 255) / 256, 256, 0, stream>>>(dst, cnt, E);
    scan1_kernel<<<nScanBlocks, 1024, 0, stream>>>(cnt, offs, part, N);
    scan2_kernel<<<1, 64, 0, stream>>>(part, offs, N, nScanBlocks);
    scan3_kernel<<<nScanBlocks, 1024, 0, stream>>>(offs, part, N);
    scatter_kernel<<<(E + 255) / 256, 256, 0, stream>>>(src, dst, offs, cur, eidx, E);

    // weight prep
    transpose_cast_kernel<<<dim3(128 / 32, 256 / 32), 256, 0, stream>>>(W1, Wt1, 128);
    transpose_cast_kernel<<<dim3(256 / 32, 256 / 32), 256, 0, stream>>>(W2, Wt2, 256);

    // layer 1
    cast_bf16_kernel<<<(N * 128 / 4 + 255) / 256, 256, 0, stream>>>(h, hb, N * 128 / 4);
    agg_mean_bf16_kernel<128><<<(N + 3) / 4, 256, 0, stream>>>(hb, offs, eidx, aggOut, N);
    gemm_mfma_kernel<128, true><<<(N + 63) / 64, 256, 0, stream>>>(aggOut, Wt1, b1, nullptr, h1b, N);

    // layer 2
    agg_mean_bf16_kernel<256><<<(N + 3) / 4, 256, 0, stream>>>(h1b, offs, eidx, aggOut, N);
    gemm_mfma_kernel<256, false><<<(N + 63) / 64, 256, 0, stream>>>(aggOut, Wt2, b2, bufB, nullptr, N);

    // readout
    gcount_kernel<<<(N + 255) / 256, 256, 0, stream>>>(gids, gcnt, N);
    readout_kernel<<<(N + RCHUNK - 1) / RCHUNK, 256, 0, stream>>>(bufB, gids, gsum, N);
    final_kernel<<<NUM_GRAPHS, 128, 0, stream>>>(gsum, gcnt, Wr1, br1, Wr2, br2, (float*)d_out);
}

// Round 5
// 374.396 us; speedup vs baseline: 2.1597x; 1.1773x over previous
//
#include <hip/hip_runtime.h>

// GCN regressor: 2x (mean-aggregate + linear+ReLU) + per-graph mean + MLP head.
// N=50000 nodes, E=800000 edges, D_IN=128, H1=256, H2=128, G=256.
// R5: graph counting via sorted-boundary detection (no atomics); otherwise R4.

#define NUM_GRAPHS 256

typedef __attribute__((ext_vector_type(8))) short bf16x8;
typedef __attribute__((ext_vector_type(4))) float f32x4;

__device__ inline unsigned short f2bf(float f) {  // round-to-nearest-even
    unsigned u = __float_as_uint(f);
    return (unsigned short)((u + 0x7fff + ((u >> 16) & 1)) >> 16);
}
__device__ inline float bflo(unsigned u) { return __uint_as_float(u << 16); }
__device__ inline float bfhi(unsigned u) { return __uint_as_float(u & 0xffff0000u); }

// ---------------- CSR build ----------------

__global__ void count_kernel(const int* __restrict__ dst, int* __restrict__ cnt, int E) {
    int e = blockIdx.x * blockDim.x + threadIdx.x;
    if (e < E) atomicAdd(&cnt[dst[e]], 1);
}

__global__ void scan1_kernel(const int* __restrict__ cnt, int* __restrict__ offs,
                             int* __restrict__ part, int N) {
    __shared__ int wsum[16];
    int tid = threadIdx.x;
    int lane = tid & 63;
    int wid = tid >> 6;
    int i = blockIdx.x * 1024 + tid;
    int v = (i < N) ? cnt[i] : 0;
    int x = v;
    #pragma unroll
    for (int d = 1; d < 64; d <<= 1) {
        int y = __shfl_up(x, d, 64);
        if (lane >= d) x += y;
    }
    if (lane == 63) wsum[wid] = x;
    __syncthreads();
    if (wid == 0) {
        int s = (lane < 16) ? wsum[lane] : 0;
        #pragma unroll
        for (int d = 1; d < 16; d <<= 1) {
            int y = __shfl_up(s, d, 64);
            if (lane >= d) s += y;
        }
        if (lane < 16) wsum[lane] = s;
    }
    __syncthreads();
    int wbase = (wid > 0) ? wsum[wid - 1] : 0;
    if (i < N) offs[i] = wbase + x - v;
    if (tid == 1023) part[blockIdx.x] = wbase + x;
}

__global__ void scan2_kernel(int* __restrict__ part, int* __restrict__ offs, int N, int P) {
    int lane = threadIdx.x;  // 64 threads, P <= 64
    int v = (lane < P) ? part[lane] : 0;
    int x = v;
    #pragma unroll
    for (int d = 1; d < 64; d <<= 1) {
        int y = __shfl_up(x, d, 64);
        if (lane >= d) x += y;
    }
    if (lane < P) part[lane] = x - v;
    if (lane == 63) offs[N] = x;
}

__global__ void scan3_kernel(int* __restrict__ offs, const int* __restrict__ part, int N) {
    int i = blockIdx.x * 1024 + threadIdx.x;
    if (i < N) offs[i] += part[blockIdx.x];
}

__global__ void scatter_kernel(const int* __restrict__ src, const int* __restrict__ dst,
                               const int* __restrict__ offs, int* __restrict__ cur,
                               int* __restrict__ eidx, int E) {
    int e = blockIdx.x * blockDim.x + threadIdx.x;
    if (e < E) {
        int d = dst[e];
        int p = offs[d] + atomicAdd(&cur[d], 1);
        eidx[p] = src[e];
    }
}

// ---------------- graph segment starts (gids sorted): gstart[g] = first node of graph g ----------------
// gstart has NUM_GRAPHS+1 entries; count(g) = gstart[g+1]-gstart[g].

__global__ void gstart_kernel(const int* __restrict__ gids, int* __restrict__ gstart, int N) {
    int n = blockIdx.x * blockDim.x + threadIdx.x;
    if (n >= N) return;
    int g = gids[n];
    int gp = (n == 0) ? -1 : gids[n - 1];
    for (int x = gp + 1; x <= g; ++x) gstart[x] = n;  // covers empty graphs
    if (n == N - 1)
        for (int x = g + 1; x <= NUM_GRAPHS; ++x) gstart[x] = N;
}

// ---------------- fp32 -> bf16 cast (layer-1 gather table) ----------------

__global__ void cast_bf16_kernel(const float* __restrict__ in, unsigned short* __restrict__ out,
                                 int total4) {
    int i = blockIdx.x * blockDim.x + threadIdx.x;
    if (i < total4) {
        float4 v = *(const float4*)(in + (size_t)i * 4);
        ushort4 o;
        o.x = f2bf(v.x); o.y = f2bf(v.y); o.z = f2bf(v.z); o.w = f2bf(v.w);
        *(ushort4*)(out + (size_t)i * 4) = o;
    }
}

// ---------------- weight transpose+cast: Wt[n][k] = bf16(W[k][n]), Ncols=256 ----------------

__global__ void transpose_cast_kernel(const float* __restrict__ W, unsigned short* __restrict__ Wt,
                                      int K) {
    __shared__ float tile[32][33];
    int k0 = blockIdx.x * 32;
    int n0 = blockIdx.y * 32;
    int tx = threadIdx.x & 31;
    int ty = threadIdx.x >> 5;  // 0..7
    #pragma unroll
    for (int i = 0; i < 4; ++i)
        tile[ty + i * 8][tx] = W[(size_t)(k0 + ty + i * 8) * 256 + n0 + tx];
    __syncthreads();
    #pragma unroll
    for (int i = 0; i < 4; ++i)
        Wt[(size_t)(n0 + ty + i * 8) * K + k0 + tx] = f2bf(tile[tx][ty + i * 8]);
}

// ---------------- mean aggregation: bf16 gather, fp32 accum, bf16 output ----------------

template <int D>
__global__ void agg_mean_bf16_kernel(const unsigned short* __restrict__ feat,
                                     const int* __restrict__ offs,
                                     const int* __restrict__ eidx,
                                     unsigned short* __restrict__ out, int N) {
    constexpr int VPL = D / 64;  // 2 or 4
    int wave = blockIdx.x * (blockDim.x >> 6) + (threadIdx.x >> 6);
    int lane = threadIdx.x & 63;
    if (wave >= N) return;
    int beg = offs[wave], end = offs[wave + 1];
    float acc[VPL];
    #pragma unroll
    for (int i = 0; i < VPL; ++i) acc[i] = 0.0f;

    int j = beg;
    for (; j + 8 <= end; j += 8) {
        int s[8];
        #pragma unroll
        for (int u = 0; u < 8; ++u) s[u] = eidx[j + u];
        if constexpr (VPL == 2) {
            unsigned v[8];
            #pragma unroll
            for (int u = 0; u < 8; ++u)
                v[u] = *(const unsigned*)(feat + (size_t)s[u] * D + lane * 2);
            #pragma unroll
            for (int u = 0; u < 8; ++u) { acc[0] += bflo(v[u]); acc[1] += bfhi(v[u]); }
        } else {
            uint2 v[8];
            #pragma unroll
            for (int u = 0; u < 8; ++u)
                v[u] = *(const uint2*)(feat + (size_t)s[u] * D + lane * 4);
            #pragma unroll
            for (int u = 0; u < 8; ++u) {
                acc[0] += bflo(v[u].x); acc[1] += bfhi(v[u].x);
                acc[2] += bflo(v[u].y); acc[3] += bfhi(v[u].y);
            }
        }
    }
    for (; j < end; ++j) {
        int s = eidx[j];
        if constexpr (VPL == 2) {
            unsigned v = *(const unsigned*)(feat + (size_t)s * D + lane * 2);
            acc[0] += bflo(v); acc[1] += bfhi(v);
        } else {
            uint2 v = *(const uint2*)(feat + (size_t)s * D + lane * 4);
            acc[0] += bflo(v.x); acc[1] += bfhi(v.x);
            acc[2] += bflo(v.y); acc[3] += bfhi(v.y);
        }
    }

    int deg = end - beg;
    float invd = 1.0f / (float)(deg > 0 ? deg : 1);
    unsigned short* orow = out + (size_t)wave * D + lane * VPL;
    if constexpr (VPL == 2) {
        ushort2 o; o.x = f2bf(acc[0] * invd); o.y = f2bf(acc[1] * invd);
        *(ushort2*)orow = o;
    } else {
        ushort4 o;
        o.x = f2bf(acc[0] * invd); o.y = f2bf(acc[1] * invd);
        o.z = f2bf(acc[2] * invd); o.w = f2bf(acc[3] * invd);
        *(ushort4*)orow = o;
    }
}

// ---------------- bf16 MFMA GEMM + bias + ReLU ----------------

template <int K, bool OBF16>
__launch_bounds__(256)
__global__ void gemm_mfma_kernel(const unsigned short* __restrict__ A,
                                 const unsigned short* __restrict__ Wt,
                                 const float* __restrict__ bias,
                                 float* __restrict__ Cf, unsigned short* __restrict__ Cb,
                                 int N) {
    constexpr int LDS = 40;
    __shared__ unsigned short As[64 * LDS];
    __shared__ unsigned short Bs[256 * LDS];

    int tid = threadIdx.x;
    int wave = tid >> 6;
    int lane = tid & 63;
    int m = lane & 15;
    int q = lane >> 4;
    int rowBase = blockIdx.x * 64;

    f32x4 acc[4][4] = {};

    for (int kc = 0; kc < K; kc += 32) {
        {
            int r = tid >> 2;
            int seg = tid & 3;
            int gr = rowBase + r;
            uint4 v = make_uint4(0, 0, 0, 0);
            if (gr < N) v = *(const uint4*)(A + (size_t)gr * K + kc + seg * 8);
            *(uint4*)&As[r * LDS + seg * 8] = v;
        }
        #pragma unroll
        for (int it = 0; it < 4; ++it) {
            int n = (tid >> 2) + it * 64;
            int seg = tid & 3;
            uint4 v = *(const uint4*)(Wt + (size_t)n * K + kc + seg * 8);
            *(uint4*)&Bs[n * LDS + seg * 8] = v;
        }
        __syncthreads();

        bf16x8 af[4], bfr[4];
        #pragma unroll
        for (int r = 0; r < 4; ++r)
            af[r] = *(const bf16x8*)&As[(r * 16 + m) * LDS + q * 8];
        #pragma unroll
        for (int c = 0; c < 4; ++c)
            bfr[c] = *(const bf16x8*)&Bs[(wave * 64 + c * 16 + m) * LDS + q * 8];
        #pragma unroll
        for (int r = 0; r < 4; ++r)
            #pragma unroll
            for (int c = 0; c < 4; ++c)
                acc[r][c] = __builtin_amdgcn_mfma_f32_16x16x32_bf16(af[r], bfr[c], acc[r][c], 0, 0, 0);
        __syncthreads();
    }

    #pragma unroll
    for (int c = 0; c < 4; ++c) {
        int col = wave * 64 + c * 16 + m;
        float bv = bias[col];
        #pragma unroll
        for (int r = 0; r < 4; ++r) {
            #pragma unroll
            for (int reg = 0; reg < 4; ++reg) {
                int grow = rowBase + r * 16 + q * 4 + reg;
                if (grow < N) {
                    float o = fmaxf(acc[r][c][reg] + bv, 0.0f);
                    if constexpr (OBF16) Cb[(size_t)grow * 256 + col] = f2bf(o);
                    else                 Cf[(size_t)grow * 256 + col] = o;
                }
            }
        }
    }
}

// ---------------- per-graph mean readout ----------------

#define RCHUNK 64
__global__ void readout_kernel(const float* __restrict__ h2, const int* __restrict__ gids,
                               float* __restrict__ gsum, int N) {
    __shared__ int sg[RCHUNK];
    int n0 = blockIdx.x * RCHUNK;
    int tid = threadIdx.x;  // 256 = feature
    int cnt = N - n0; if (cnt > RCHUNK) cnt = RCHUNK;
    if (cnt <= 0) return;
    for (int i = tid; i < cnt; i += 256) sg[i] = gids[n0 + i];
    __syncthreads();
    int curg = sg[0];
    float acc = 0.0f;
    int i = 0;
    for (; i + 8 <= cnt; i += 8) {
        float v[8];
        #pragma unroll
        for (int u = 0; u < 8; ++u)
            v[u] = h2[(size_t)(n0 + i + u) * 256 + tid];
        #pragma unroll
        for (int u = 0; u < 8; ++u) {
            int g = sg[i + u];
            if (g != curg) {
                atomicAdd(&gsum[curg * 256 + tid], acc);
                acc = 0.0f;
                curg = g;
            }
            acc += v[u];
        }
    }
    for (; i < cnt; ++i) {
        int g = sg[i];
        if (g != curg) {
            atomicAdd(&gsum[curg * 256 + tid], acc);
            acc = 0.0f;
            curg = g;
        }
        acc += h2[(size_t)(n0 + i) * 256 + tid];
    }
    atomicAdd(&gsum[curg * 256 + tid], acc);
}

// ---------------- MLP head ----------------

__global__ void final_kernel(const float* __restrict__ gsum, const int* __restrict__ gstart,
                             const float* __restrict__ Wr1, const float* __restrict__ br1,
                             const float* __restrict__ Wr2, const float* __restrict__ br2,
                             float* __restrict__ out) {
    int g = blockIdx.x;
    int j = threadIdx.x;  // 128
    int c = gstart[g + 1] - gstart[g];
    float invc = 1.0f / (float)(c > 0 ? c : 1);
    const float* gs = gsum + g * 256;
    float acc = br1[j];
    for (int k = 0; k < 256; ++k)
        acc += (gs[k] * invc) * Wr1[k * 128 + j];
    float p = acc * Wr2[j];
    #pragma unroll
    for (int d = 32; d > 0; d >>= 1) p += __shfl_down(p, d, 64);
    __shared__ float ws2[2];
    if ((j & 63) == 0) ws2[j >> 6] = p;
    __syncthreads();
    if (j == 0) out[g] = ws2[0] + ws2[1] + br2[0];
}

// ---------------- launch ----------------

extern "C" void kernel_launch(void* const* d_in, const int* in_sizes, int n_in,
                              void* d_out, int out_size, void* d_ws, size_t ws_size,
                              hipStream_t stream) {
    const float* h    = (const float*)d_in[0];
    const int*   src  = (const int*)d_in[1];
    const int*   dst  = (const int*)d_in[2];
    const int*   gids = (const int*)d_in[3];
    const float* W1   = (const float*)d_in[4];
    const float* b1   = (const float*)d_in[5];
    const float* W2   = (const float*)d_in[6];
    const float* b2   = (const float*)d_in[7];
    const float* Wr1  = (const float*)d_in[8];
    const float* br1  = (const float*)d_in[9];
    const float* Wr2  = (const float*)d_in[10];
    const float* br2  = (const float*)d_in[11];

    int N = in_sizes[0] / 128;
    int E = in_sizes[1];
    int nScanBlocks = (N + 1023) / 1024;  // 49 for N=50000, must be <= 64

    // workspace. R1 (N*256*4 B) time-shares: hb -> h1b -> bufB.
    // R2 (N*256*2 B) time-shares aggOut1/aggOut2.
    char* w = (char*)d_ws;
    char* R1 = w;                       w += (size_t)N * 256 * sizeof(float);
    char* R2 = w;                       w += (size_t)N * 256 * sizeof(unsigned short);
    unsigned short* hb   = (unsigned short*)R1;
    unsigned short* h1b  = (unsigned short*)R1;
    float*          bufB = (float*)R1;
    unsigned short* aggOut = (unsigned short*)R2;
    int* cnt    = (int*)w;              w += (size_t)N * sizeof(int);
    int* offs   = (int*)w;              w += (size_t)(N + 1) * sizeof(int);
    int* cur    = (int*)w;              w += (size_t)N * sizeof(int);
    int* eidx   = (int*)w;              w += (size_t)E * sizeof(int);
    int* part   = (int*)w;              w += 64 * sizeof(int);
    unsigned short* Wt1 = (unsigned short*)w;  w += 256 * 128 * sizeof(unsigned short);
    unsigned short* Wt2 = (unsigned short*)w;  w += 256 * 256 * sizeof(unsigned short);
    float* gsum = (float*)w;            w += (size_t)NUM_GRAPHS * 256 * sizeof(float);
    int* gstart = (int*)w;              w += (size_t)(NUM_GRAPHS + 1) * sizeof(int);

    hipMemsetAsync(cnt, 0, (size_t)N * sizeof(int), stream);
    hipMemsetAsync(cur, 0, (size_t)N * sizeof(int), stream);
    hipMemsetAsync(gsum, 0, (size_t)NUM_GRAPHS * 256 * sizeof(float), stream);

    count_kernel<<<(E + 255) / 256, 256, 0, stream>>>(dst, cnt, E);
    scan1_kernel<<<nScanBlocks, 1024, 0, stream>>>(cnt, offs, part, N);
    scan2_kernel<<<1, 64, 0, stream>>>(part, offs, N, nScanBlocks);
    scan3_kernel<<<nScanBlocks, 1024, 0, stream>>>(offs, part, N);
    scatter_kernel<<<(E + 255) / 256, 256, 0, stream>>>(src, dst, offs, cur, eidx, E);
    gstart_kernel<<<(N + 255) / 256, 256, 0, stream>>>(gids, gstart, N);

    // weight prep
    transpose_cast_kernel<<<dim3(128 / 32, 256 / 32), 256, 0, stream>>>(W1, Wt1, 128);
    transpose_cast_kernel<<<dim3(256 / 32, 256 / 32), 256, 0, stream>>>(W2, Wt2, 256);

    // layer 1
    cast_bf16_kernel<<<(N * 128 / 4 + 255) / 256, 256, 0, stream>>>(h, hb, N * 128 / 4);
    agg_mean_bf16_kernel<128><<<(N + 3) / 4, 256, 0, stream>>>(hb, offs, eidx, aggOut, N);
    gemm_mfma_kernel<128, true><<<(N + 63) / 64, 256, 0, stream>>>(aggOut, Wt1, b1, nullptr, h1b, N);

    // layer 2
    agg_mean_bf16_kernel<256><<<(N + 3) / 4, 256, 0, stream>>>(h1b, offs, eidx, aggOut, N);
    gemm_mfma_kernel<256, false><<<(N + 63) / 64, 256, 0, stream>>>(aggOut, Wt2, b2, bufB, nullptr, N);

    // readout
    readout_kernel<<<(N + RCHUNK - 1) / RCHUNK, 256, 0, stream>>>(bufB, gids, gsum, N);
    final_kernel<<<NUM_GRAPHS, 128, 0, stream>>>(gsum, gstart, Wr1, br1, Wr2, br2, (float*)d_out);
}